// Round 1
// baseline (566.388 us; speedup 1.0000x reference)
//
#include <hip/hip_runtime.h>

#define BN_EPS_F 1e-5f

// ---------------- k0b: W (128x128, row-major [j][k]) -> Wt[k][j] ----------------
__global__ void transpose_W_kernel(const float* __restrict__ W, float* __restrict__ Wt) {
  int idx = blockIdx.x * 256 + threadIdx.x;
  if (idx < 128 * 128) {
    int j = idx >> 7, k = idx & 127;
    Wt[(k << 7) + j] = W[idx];
  }
}

// ---------------- k1: h = x @ W.T + b  (n % 32 == 0 assumed; n=100000=3125*32) ----------------
// Block: 256 thr = 8 groups of 32 lanes. Group g computes nodes tile+4g..tile+4g+3,
// lane (t&31) computes feature quad jq=4*(t&31). W read from global Wt (L1/L2 resident, 64KB).
__global__ __launch_bounds__(256) void linear_kernel(
    const float* __restrict__ x, const float* __restrict__ Wt,
    const float* __restrict__ bias, float* __restrict__ h, int n_nodes) {
  __shared__ float xt[32 * 128];
  const int t = threadIdx.x;
  const int tile = blockIdx.x << 5;
  {
    const float4* xg = reinterpret_cast<const float4*>(x) + ((size_t)tile << 5);
    float4* xl = reinterpret_cast<float4*>(xt);
#pragma unroll
    for (int i = 0; i < 4; ++i) xl[t + i * 256] = xg[t + i * 256];
  }
  __syncthreads();
  const int jq = (t & 31) << 2;
  const int g = t >> 5;
  const float* xr0 = &xt[(g * 4 + 0) << 7];
  const float* xr1 = &xt[(g * 4 + 1) << 7];
  const float* xr2 = &xt[(g * 4 + 2) << 7];
  const float* xr3 = &xt[(g * 4 + 3) << 7];
  float4 a0 = {0, 0, 0, 0}, a1 = {0, 0, 0, 0}, a2 = {0, 0, 0, 0}, a3 = {0, 0, 0, 0};
#pragma unroll 8
  for (int k = 0; k < 128; ++k) {
    float4 w = *reinterpret_cast<const float4*>(&Wt[(k << 7) + jq]);
    float x0 = xr0[k], x1 = xr1[k], x2 = xr2[k], x3 = xr3[k];
    a0.x = fmaf(x0, w.x, a0.x); a0.y = fmaf(x0, w.y, a0.y);
    a0.z = fmaf(x0, w.z, a0.z); a0.w = fmaf(x0, w.w, a0.w);
    a1.x = fmaf(x1, w.x, a1.x); a1.y = fmaf(x1, w.y, a1.y);
    a1.z = fmaf(x1, w.z, a1.z); a1.w = fmaf(x1, w.w, a1.w);
    a2.x = fmaf(x2, w.x, a2.x); a2.y = fmaf(x2, w.y, a2.y);
    a2.z = fmaf(x2, w.z, a2.z); a2.w = fmaf(x2, w.w, a2.w);
    a3.x = fmaf(x3, w.x, a3.x); a3.y = fmaf(x3, w.y, a3.y);
    a3.z = fmaf(x3, w.z, a3.z); a3.w = fmaf(x3, w.w, a3.w);
  }
  float4 bb = *reinterpret_cast<const float4*>(&bias[jq]);
  a0.x += bb.x; a0.y += bb.y; a0.z += bb.z; a0.w += bb.w;
  a1.x += bb.x; a1.y += bb.y; a1.z += bb.z; a1.w += bb.w;
  a2.x += bb.x; a2.y += bb.y; a2.z += bb.z; a2.w += bb.w;
  a3.x += bb.x; a3.y += bb.y; a3.z += bb.z; a3.w += bb.w;
  const int nb = tile + (g << 2);
  *reinterpret_cast<float4*>(&h[((size_t)(nb + 0) << 7) + jq]) = a0;
  *reinterpret_cast<float4*>(&h[((size_t)(nb + 1) << 7) + jq]) = a1;
  *reinterpret_cast<float4*>(&h[((size_t)(nb + 2) << 7) + jq]) = a2;
  *reinterpret_cast<float4*>(&h[((size_t)(nb + 3) << 7) + jq]) = a3;
}

// ---------------- k2: degree histogram ----------------
__global__ void hist_kernel(const int* __restrict__ row, int* __restrict__ hist,
                            int e_total, int n) {
  int i = blockIdx.x * blockDim.x + threadIdx.x;
  const int stride = gridDim.x * blockDim.x;
  for (; i < e_total; i += stride) {
    unsigned r = (unsigned)row[i];
    if (r < (unsigned)n) atomicAdd(&hist[r], 1);
  }
}

// ---------------- k3a: per-1024-chunk sums ----------------
__global__ void scan_chunksum_kernel(const int* __restrict__ hist, int* __restrict__ bsums, int n) {
  __shared__ int sd[256];
  const int t = threadIdx.x;
  const int base = blockIdx.x * 1024 + t * 4;
  int s = 0;
#pragma unroll
  for (int i = 0; i < 4; ++i) {
    int idx = base + i;
    if (idx < n) s += hist[idx];
  }
  sd[t] = s;
  __syncthreads();
  for (int off = 128; off > 0; off >>= 1) {
    if (t < off) sd[t] += sd[t + off];
    __syncthreads();
  }
  if (t == 0) bsums[blockIdx.x] = sd[0];
}

// ---------------- k3b: exclusive scan of chunk sums (nchunk <= 128) ----------------
__global__ void scan_offsets_kernel(const int* __restrict__ bsums, int* __restrict__ coff,
                                    int* __restrict__ rowptr, int nchunk, int n, int e_total) {
  __shared__ int sd[128];
  const int t = threadIdx.x;
  int orig = (t < nchunk) ? bsums[t] : 0;
  sd[t] = orig;
  __syncthreads();
  for (int off = 1; off < 128; off <<= 1) {
    int v = (t >= off) ? sd[t - off] : 0;
    __syncthreads();
    sd[t] += v;
    __syncthreads();
  }
  coff[t] = sd[t] - orig;
  if (t == 0) rowptr[n] = e_total;
}

// ---------------- k3c: intra-chunk exclusive scan -> rowptr, cursor ----------------
__global__ void scan_final_kernel(const int* __restrict__ hist, const int* __restrict__ coff,
                                  int* __restrict__ rowptr, int* __restrict__ cursor, int n) {
  __shared__ int sd[256];
  const int t = threadIdx.x;
  const int base = blockIdx.x * 1024 + t * 4;
  int v0 = 0, v1 = 0, v2 = 0, v3 = 0;
  if (base + 0 < n) v0 = hist[base + 0];
  if (base + 1 < n) v1 = hist[base + 1];
  if (base + 2 < n) v2 = hist[base + 2];
  if (base + 3 < n) v3 = hist[base + 3];
  const int own = v0 + v1 + v2 + v3;
  sd[t] = own;
  __syncthreads();
  for (int off = 1; off < 256; off <<= 1) {
    int v = (t >= off) ? sd[t - off] : 0;
    __syncthreads();
    sd[t] += v;
    __syncthreads();
  }
  int excl = sd[t] - own + coff[blockIdx.x];
  if (base + 0 < n) { rowptr[base + 0] = excl; cursor[base + 0] = excl; excl += v0; }
  if (base + 1 < n) { rowptr[base + 1] = excl; cursor[base + 1] = excl; excl += v1; }
  if (base + 2 < n) { rowptr[base + 2] = excl; cursor[base + 2] = excl; excl += v2; }
  if (base + 3 < n) { rowptr[base + 3] = excl; cursor[base + 3] = excl; excl += v3; }
}

// ---------------- k4: scatter edges into CSR order ----------------
__global__ void scatter_kernel(const int* __restrict__ row, const int* __restrict__ col,
                               int* __restrict__ cursor, int* __restrict__ scol,
                               int e_total, int n) {
  int i = blockIdx.x * blockDim.x + threadIdx.x;
  const int stride = gridDim.x * blockDim.x;
  for (; i < e_total; i += stride) {
    unsigned r = (unsigned)row[i];
    if (r < (unsigned)n) {
      int pos = atomicAdd(&cursor[r], 1);
      scol[pos] = col[i];
    }
  }
}

// ---------------- k5: out_pre = h + mean-agg; accumulate per-feature sum/sumsq ----------------
// One wave (64 lanes) per node; lane handles features 2*lane, 2*lane+1 (float2, 512B/row coalesced).
__global__ __launch_bounds__(256) void agg_kernel(
    const float* __restrict__ h, const int* __restrict__ rowptr,
    const int* __restrict__ scol, float* __restrict__ out,
    float* __restrict__ stat_sum, float* __restrict__ stat_sumsq, int n_nodes) {
  const int t = threadIdx.x;
  const int wave = t >> 6, lane = t & 63;
  const int f0 = lane << 1;
  float lsx = 0.f, lsy = 0.f, lqx = 0.f, lqy = 0.f;
  const int wstride = gridDim.x << 2;
  for (int node = (blockIdx.x << 2) + wave; node < n_nodes; node += wstride) {
    const int r0 = rowptr[node], r1 = rowptr[node + 1];
    float s0x = 0.f, s0y = 0.f, s1x = 0.f, s1y = 0.f;
    int e = r0;
    for (; e + 1 < r1; e += 2) {
      int c0 = scol[e], c1 = scol[e + 1];
      float2 v0 = *reinterpret_cast<const float2*>(&h[((size_t)c0 << 7) + f0]);
      float2 v1 = *reinterpret_cast<const float2*>(&h[((size_t)c1 << 7) + f0]);
      s0x += v0.x; s0y += v0.y;
      s1x += v1.x; s1y += v1.y;
    }
    if (e < r1) {
      int c0 = scol[e];
      float2 v0 = *reinterpret_cast<const float2*>(&h[((size_t)c0 << 7) + f0]);
      s0x += v0.x; s0y += v0.y;
    }
    const float inv = 1.0f / ((float)(r1 - r0) + 1e-8f);
    float2 hv = *reinterpret_cast<const float2*>(&h[((size_t)node << 7) + f0]);
    const float vx = fmaf(s0x + s1x, inv, hv.x);
    const float vy = fmaf(s0y + s1y, inv, hv.y);
    float2 o; o.x = vx; o.y = vy;
    *reinterpret_cast<float2*>(&out[((size_t)node << 7) + f0]) = o;
    lsx += vx; lsy += vy;
    lqx = fmaf(vx, vx, lqx); lqy = fmaf(vy, vy, lqy);
  }
  __shared__ float reds[4][128];
  __shared__ float redq[4][128];
  reds[wave][f0] = lsx; reds[wave][f0 + 1] = lsy;
  redq[wave][f0] = lqx; redq[wave][f0 + 1] = lqy;
  __syncthreads();
  if (t < 128) {
    float s = reds[0][t] + reds[1][t] + reds[2][t] + reds[3][t];
    float q = redq[0][t] + redq[1][t] + redq[2][t] + redq[3][t];
    atomicAdd(&stat_sum[t], s);
    atomicAdd(&stat_sumsq[t], q);
  }
}

// ---------------- k6: BN stats -> per-feature scale/shift ----------------
__global__ void finalize_kernel(const float* __restrict__ ssum, const float* __restrict__ ssq,
                                const float* __restrict__ gamma, const float* __restrict__ beta,
                                float* __restrict__ scale, float* __restrict__ shift, int n) {
  const int t = threadIdx.x;  // 128
  const float invn = 1.0f / (float)n;
  float mean = ssum[t] * invn;
  float var = ssq[t] * invn - mean * mean;
  float sc = gamma[t] * rsqrtf(var + BN_EPS_F);
  scale[t] = sc;
  shift[t] = beta[t] - mean * sc;
}

// ---------------- k7: BN apply in-place on d_out ----------------
__global__ __launch_bounds__(256) void bn_kernel(float* __restrict__ out,
                                                 const float* __restrict__ scale,
                                                 const float* __restrict__ shift, int n_nodes) {
  __shared__ float sc[128], sh[128];
  if (threadIdx.x < 128) {
    sc[threadIdx.x] = scale[threadIdx.x];
    sh[threadIdx.x] = shift[threadIdx.x];
  }
  __syncthreads();
  const int total4 = n_nodes * 32;
  int i = blockIdx.x * 256 + threadIdx.x;
  const int stride = gridDim.x * 256;
  float4* o4 = reinterpret_cast<float4*>(out);
  for (; i < total4; i += stride) {
    float4 v = o4[i];
    const int fq = (i & 31) << 2;
    v.x = fmaf(v.x, sc[fq + 0], sh[fq + 0]);
    v.y = fmaf(v.y, sc[fq + 1], sh[fq + 1]);
    v.z = fmaf(v.z, sc[fq + 2], sh[fq + 2]);
    v.w = fmaf(v.w, sc[fq + 3], sh[fq + 3]);
    o4[i] = v;
  }
}

extern "C" void kernel_launch(void* const* d_in, const int* in_sizes, int n_in,
                              void* d_out, int out_size, void* d_ws, size_t ws_size,
                              hipStream_t stream) {
  const float* x     = (const float*)d_in[0];
  const int*   ei    = (const int*)d_in[1];
  const float* W     = (const float*)d_in[2];
  const float* bias  = (const float*)d_in[3];
  const float* gamma = (const float*)d_in[4];
  const float* beta  = (const float*)d_in[5];
  const int n = in_sizes[0] / 128;   // 100000
  const int e = in_sizes[1] / 2;     // 1600000
  const int* row = ei;
  const int* col = ei + e;
  float* out = (float*)d_out;

  char* base = (char*)d_ws;
  size_t off = 0;
  auto carve = [&](size_t bytes) -> char* {
    char* p = base + off;
    off += (bytes + 255) & ~(size_t)255;
    return p;
  };
  float* h      = (float*)carve((size_t)n * 128 * 4);  // 51.2 MB
  float* Wt     = (float*)carve(128 * 128 * 4);        // 64 KB
  int*   scol   = (int*)carve((size_t)e * 4);          // 6.4 MB
  int*   rowptr = (int*)carve((size_t)(n + 1) * 4);
  int*   cursor = (int*)carve((size_t)n * 4);
  char*  zbase  = base + off;
  int*   hist   = (int*)carve((size_t)n * 4);
  float* ssum   = (float*)carve(512);
  float* ssq    = (float*)carve(512);
  size_t zlen   = (size_t)((base + off) - zbase);
  float* scale  = (float*)carve(512);
  float* shift  = (float*)carve(512);
  int*   bsums  = (int*)carve(512);
  int*   coff   = (int*)carve(512);
  (void)ws_size; (void)n_in; (void)out_size;

  const int nchunk = (n + 1023) / 1024;  // 98 (<=128 required)

  hipMemsetAsync(zbase, 0, zlen, stream);
  transpose_W_kernel<<<64, 256, 0, stream>>>(W, Wt);
  linear_kernel<<<n / 32, 256, 0, stream>>>(x, Wt, bias, h, n);
  hist_kernel<<<2048, 256, 0, stream>>>(row, hist, e, n);
  scan_chunksum_kernel<<<nchunk, 256, 0, stream>>>(hist, bsums, n);
  scan_offsets_kernel<<<1, 128, 0, stream>>>(bsums, coff, rowptr, nchunk, n, e);
  scan_final_kernel<<<nchunk, 256, 0, stream>>>(hist, coff, rowptr, cursor, n);
  scatter_kernel<<<2048, 256, 0, stream>>>(row, col, cursor, scol, e, n);
  agg_kernel<<<3200, 256, 0, stream>>>(h, rowptr, scol, out, ssum, ssq, n);
  finalize_kernel<<<1, 128, 0, stream>>>(ssum, ssq, gamma, beta, scale, shift, n);
  bn_kernel<<<2048, 256, 0, stream>>>(out, scale, shift, n);
}

// Round 3
// 513.654 us; speedup vs baseline: 1.1027x; 1.1027x over previous
//
#include <hip/hip_runtime.h>

#define BN_EPS_F 1e-5f

static __device__ __forceinline__ float bf2f(unsigned short u) {
  union { unsigned int i; float f; } c; c.i = ((unsigned int)u) << 16; return c.f;
}
static __device__ __forceinline__ unsigned short f2bf(float f) {
  union { float f; unsigned int i; } c; c.f = f;
  unsigned int r = c.i + 0x7FFFu + ((c.i >> 16) & 1u);
  return (unsigned short)(r >> 16);
}

// ---------------- k0b: W (128x128, row-major [j][k]) -> Wt[k][j] ----------------
__global__ void transpose_W_kernel(const float* __restrict__ W, float* __restrict__ Wt) {
  int idx = blockIdx.x * 256 + threadIdx.x;
  if (idx < 128 * 128) {
    int j = idx >> 7, k = idx & 127;
    Wt[(k << 7) + j] = W[idx];
  }
}

// ---------------- k1: h = x @ W.T + b -> bf16 h ----------------
__global__ __launch_bounds__(256) void linear_kernel(
    const float* __restrict__ x, const float* __restrict__ Wt,
    const float* __restrict__ bias, unsigned short* __restrict__ h, int n_nodes) {
  __shared__ float xt[32 * 128];
  const int t = threadIdx.x;
  const int tile = blockIdx.x << 5;
  {
    const float4* xg = reinterpret_cast<const float4*>(x) + ((size_t)tile << 5);
    float4* xl = reinterpret_cast<float4*>(xt);
#pragma unroll
    for (int i = 0; i < 4; ++i) xl[t + i * 256] = xg[t + i * 256];
  }
  __syncthreads();
  const int jq = (t & 31) << 2;
  const int g = t >> 5;
  const float* xr0 = &xt[(g * 4 + 0) << 7];
  const float* xr1 = &xt[(g * 4 + 1) << 7];
  const float* xr2 = &xt[(g * 4 + 2) << 7];
  const float* xr3 = &xt[(g * 4 + 3) << 7];
  float4 a0 = {0, 0, 0, 0}, a1 = {0, 0, 0, 0}, a2 = {0, 0, 0, 0}, a3 = {0, 0, 0, 0};
#pragma unroll 8
  for (int k = 0; k < 128; ++k) {
    float4 w = *reinterpret_cast<const float4*>(&Wt[(k << 7) + jq]);
    float x0 = xr0[k], x1 = xr1[k], x2 = xr2[k], x3 = xr3[k];
    a0.x = fmaf(x0, w.x, a0.x); a0.y = fmaf(x0, w.y, a0.y);
    a0.z = fmaf(x0, w.z, a0.z); a0.w = fmaf(x0, w.w, a0.w);
    a1.x = fmaf(x1, w.x, a1.x); a1.y = fmaf(x1, w.y, a1.y);
    a1.z = fmaf(x1, w.z, a1.z); a1.w = fmaf(x1, w.w, a1.w);
    a2.x = fmaf(x2, w.x, a2.x); a2.y = fmaf(x2, w.y, a2.y);
    a2.z = fmaf(x2, w.z, a2.z); a2.w = fmaf(x2, w.w, a2.w);
    a3.x = fmaf(x3, w.x, a3.x); a3.y = fmaf(x3, w.y, a3.y);
    a3.z = fmaf(x3, w.z, a3.z); a3.w = fmaf(x3, w.w, a3.w);
  }
  float4 bb = *reinterpret_cast<const float4*>(&bias[jq]);
  a0.x += bb.x; a0.y += bb.y; a0.z += bb.z; a0.w += bb.w;
  a1.x += bb.x; a1.y += bb.y; a1.z += bb.z; a1.w += bb.w;
  a2.x += bb.x; a2.y += bb.y; a2.z += bb.z; a2.w += bb.w;
  a3.x += bb.x; a3.y += bb.y; a3.z += bb.z; a3.w += bb.w;
  const int nb = tile + (g << 2);
  ushort4 p0 = {f2bf(a0.x), f2bf(a0.y), f2bf(a0.z), f2bf(a0.w)};
  ushort4 p1 = {f2bf(a1.x), f2bf(a1.y), f2bf(a1.z), f2bf(a1.w)};
  ushort4 p2 = {f2bf(a2.x), f2bf(a2.y), f2bf(a2.z), f2bf(a2.w)};
  ushort4 p3 = {f2bf(a3.x), f2bf(a3.y), f2bf(a3.z), f2bf(a3.w)};
  *reinterpret_cast<ushort4*>(&h[((size_t)(nb + 0) << 7) + jq]) = p0;
  *reinterpret_cast<ushort4*>(&h[((size_t)(nb + 1) << 7) + jq]) = p1;
  *reinterpret_cast<ushort4*>(&h[((size_t)(nb + 2) << 7) + jq]) = p2;
  *reinterpret_cast<ushort4*>(&h[((size_t)(nb + 3) << 7) + jq]) = p3;
}

// ---------------- k2: degree histogram ----------------
__global__ void hist_kernel(const int* __restrict__ row, int* __restrict__ hist,
                            int e_total, int n) {
  int i = blockIdx.x * blockDim.x + threadIdx.x;
  const int stride = gridDim.x * blockDim.x;
  for (; i < e_total; i += stride) {
    unsigned r = (unsigned)row[i];
    if (r < (unsigned)n) atomicAdd(&hist[r], 1);
  }
}

// ---------------- k3a: per-1024-chunk sums ----------------
__global__ void scan_chunksum_kernel(const int* __restrict__ hist, int* __restrict__ bsums, int n) {
  __shared__ int sd[256];
  const int t = threadIdx.x;
  const int base = blockIdx.x * 1024 + t * 4;
  int s = 0;
#pragma unroll
  for (int i = 0; i < 4; ++i) {
    int idx = base + i;
    if (idx < n) s += hist[idx];
  }
  sd[t] = s;
  __syncthreads();
  for (int off = 128; off > 0; off >>= 1) {
    if (t < off) sd[t] += sd[t + off];
    __syncthreads();
  }
  if (t == 0) bsums[blockIdx.x] = sd[0];
}

// ---------------- k3b: exclusive scan of chunk sums (nchunk <= 128) ----------------
__global__ void scan_offsets_kernel(const int* __restrict__ bsums, int* __restrict__ coff,
                                    int* __restrict__ rowptr, int nchunk, int n, int e_total) {
  __shared__ int sd[128];
  const int t = threadIdx.x;
  int orig = (t < nchunk) ? bsums[t] : 0;
  sd[t] = orig;
  __syncthreads();
  for (int off = 1; off < 128; off <<= 1) {
    int v = (t >= off) ? sd[t - off] : 0;
    __syncthreads();
    sd[t] += v;
    __syncthreads();
  }
  coff[t] = sd[t] - orig;
  if (t == 0) rowptr[n] = e_total;
}

// ---------------- k3c: intra-chunk exclusive scan -> rowptr, cursor ----------------
__global__ void scan_final_kernel(const int* __restrict__ hist, const int* __restrict__ coff,
                                  int* __restrict__ rowptr, int* __restrict__ cursor, int n) {
  __shared__ int sd[256];
  const int t = threadIdx.x;
  const int base = blockIdx.x * 1024 + t * 4;
  int v0 = 0, v1 = 0, v2 = 0, v3 = 0;
  if (base + 0 < n) v0 = hist[base + 0];
  if (base + 1 < n) v1 = hist[base + 1];
  if (base + 2 < n) v2 = hist[base + 2];
  if (base + 3 < n) v3 = hist[base + 3];
  const int own = v0 + v1 + v2 + v3;
  sd[t] = own;
  __syncthreads();
  for (int off = 1; off < 256; off <<= 1) {
    int v = (t >= off) ? sd[t - off] : 0;
    __syncthreads();
    sd[t] += v;
    __syncthreads();
  }
  int excl = sd[t] - own + coff[blockIdx.x];
  if (base + 0 < n) { rowptr[base + 0] = excl; cursor[base + 0] = excl; excl += v0; }
  if (base + 1 < n) { rowptr[base + 1] = excl; cursor[base + 1] = excl; excl += v1; }
  if (base + 2 < n) { rowptr[base + 2] = excl; cursor[base + 2] = excl; excl += v2; }
  if (base + 3 < n) { rowptr[base + 3] = excl; cursor[base + 3] = excl; excl += v3; }
}

// ---------------- k4: scatter edges into CSR order ----------------
__global__ void scatter_kernel(const int* __restrict__ row, const int* __restrict__ col,
                               int* __restrict__ cursor, int* __restrict__ scol,
                               int e_total, int n) {
  int i = blockIdx.x * blockDim.x + threadIdx.x;
  const int stride = gridDim.x * blockDim.x;
  for (; i < e_total; i += stride) {
    unsigned r = (unsigned)row[i];
    if (r < (unsigned)n) {
      int pos = atomicAdd(&cursor[r], 1);
      scol[pos] = col[i];
    }
  }
}

// ---------------- k5: out_pre = h + mean-agg (bf16 gather); accumulate sum/sumsq ----------------
// One wave (64 lanes) per node; lane handles features 2*lane, 2*lane+1 (ushort2 = 4B, 256B/row).
__global__ __launch_bounds__(256) void agg_kernel(
    const unsigned short* __restrict__ h, const int* __restrict__ rowptr,
    const int* __restrict__ scol, float* __restrict__ out,
    float* __restrict__ stat_sum, float* __restrict__ stat_sumsq, int n_nodes) {
  const int t = threadIdx.x;
  const int wave = t >> 6, lane = t & 63;
  const int f0 = lane << 1;
  float lsx = 0.f, lsy = 0.f, lqx = 0.f, lqy = 0.f;
  const int wstride = gridDim.x << 2;
  for (int node = (blockIdx.x << 2) + wave; node < n_nodes; node += wstride) {
    const int r0 = rowptr[node], r1 = rowptr[node + 1];
    ushort2 hv = *reinterpret_cast<const ushort2*>(&h[((size_t)node << 7) + f0]);
    float s0x = 0.f, s0y = 0.f, s1x = 0.f, s1y = 0.f;
    int e = r0;
    for (; e + 3 < r1; e += 4) {
      int c0 = scol[e], c1 = scol[e + 1], c2 = scol[e + 2], c3 = scol[e + 3];
      ushort2 v0 = *reinterpret_cast<const ushort2*>(&h[((size_t)c0 << 7) + f0]);
      ushort2 v1 = *reinterpret_cast<const ushort2*>(&h[((size_t)c1 << 7) + f0]);
      ushort2 v2 = *reinterpret_cast<const ushort2*>(&h[((size_t)c2 << 7) + f0]);
      ushort2 v3 = *reinterpret_cast<const ushort2*>(&h[((size_t)c3 << 7) + f0]);
      s0x += bf2f(v0.x); s0y += bf2f(v0.y);
      s1x += bf2f(v1.x); s1y += bf2f(v1.y);
      s0x += bf2f(v2.x); s0y += bf2f(v2.y);
      s1x += bf2f(v3.x); s1y += bf2f(v3.y);
    }
    for (; e < r1; ++e) {
      int c0 = scol[e];
      ushort2 v0 = *reinterpret_cast<const ushort2*>(&h[((size_t)c0 << 7) + f0]);
      s0x += bf2f(v0.x); s0y += bf2f(v0.y);
    }
    const float inv = 1.0f / ((float)(r1 - r0) + 1e-8f);
    const float vx = fmaf(s0x + s1x, inv, bf2f(hv.x));
    const float vy = fmaf(s0y + s1y, inv, bf2f(hv.y));
    float2 o; o.x = vx; o.y = vy;
    *reinterpret_cast<float2*>(&out[((size_t)node << 7) + f0]) = o;
    lsx += vx; lsy += vy;
    lqx = fmaf(vx, vx, lqx); lqy = fmaf(vy, vy, lqy);
  }
  __shared__ float reds[4][128];
  __shared__ float redq[4][128];
  reds[wave][f0] = lsx; reds[wave][f0 + 1] = lsy;
  redq[wave][f0] = lqx; redq[wave][f0 + 1] = lqy;
  __syncthreads();
  if (t < 128) {
    float s = reds[0][t] + reds[1][t] + reds[2][t] + reds[3][t];
    float q = redq[0][t] + redq[1][t] + redq[2][t] + redq[3][t];
    atomicAdd(&stat_sum[t], s);
    atomicAdd(&stat_sumsq[t], q);
  }
}

// ---------------- k6: BN stats -> per-feature scale/shift ----------------
__global__ void finalize_kernel(const float* __restrict__ ssum, const float* __restrict__ ssq,
                                const float* __restrict__ gamma, const float* __restrict__ beta,
                                float* __restrict__ scale, float* __restrict__ shift, int n) {
  const int t = threadIdx.x;  // 128
  const float invn = 1.0f / (float)n;
  float mean = ssum[t] * invn;
  float var = ssq[t] * invn - mean * mean;
  float sc = gamma[t] * rsqrtf(var + BN_EPS_F);
  scale[t] = sc;
  shift[t] = beta[t] - mean * sc;
}

// ---------------- k7: BN apply in-place on d_out ----------------
__global__ __launch_bounds__(256) void bn_kernel(float* __restrict__ out,
                                                 const float* __restrict__ scale,
                                                 const float* __restrict__ shift, int n_nodes) {
  __shared__ float sc[128], sh[128];
  if (threadIdx.x < 128) {
    sc[threadIdx.x] = scale[threadIdx.x];
    sh[threadIdx.x] = shift[threadIdx.x];
  }
  __syncthreads();
  const int total4 = n_nodes * 32;
  int i = blockIdx.x * 256 + threadIdx.x;
  const int stride = gridDim.x * 256;
  float4* o4 = reinterpret_cast<float4*>(out);
  for (; i < total4; i += stride) {
    float4 v = o4[i];
    const int fq = (i & 31) << 2;
    v.x = fmaf(v.x, sc[fq + 0], sh[fq + 0]);
    v.y = fmaf(v.y, sc[fq + 1], sh[fq + 1]);
    v.z = fmaf(v.z, sc[fq + 2], sh[fq + 2]);
    v.w = fmaf(v.w, sc[fq + 3], sh[fq + 3]);
    o4[i] = v;
  }
}

extern "C" void kernel_launch(void* const* d_in, const int* in_sizes, int n_in,
                              void* d_out, int out_size, void* d_ws, size_t ws_size,
                              hipStream_t stream) {
  const float* x     = (const float*)d_in[0];
  const int*   ei    = (const int*)d_in[1];
  const float* W     = (const float*)d_in[2];
  const float* bias  = (const float*)d_in[3];
  const float* gamma = (const float*)d_in[4];
  const float* beta  = (const float*)d_in[5];
  const int n = in_sizes[0] / 128;   // 100000
  const int e = in_sizes[1] / 2;     // 1600000
  const int* row = ei;
  const int* col = ei + e;
  float* out = (float*)d_out;

  char* base = (char*)d_ws;
  size_t off = 0;
  auto carve = [&](size_t bytes) -> char* {
    char* p = base + off;
    off += (bytes + 255) & ~(size_t)255;
    return p;
  };
  unsigned short* h = (unsigned short*)carve((size_t)n * 128 * 2);  // 25.6 MB
  float* Wt     = (float*)carve(128 * 128 * 4);                     // 64 KB
  int*   scol   = (int*)carve((size_t)e * 4);                       // 6.4 MB
  int*   rowptr = (int*)carve((size_t)(n + 1) * 4);
  int*   cursor = (int*)carve((size_t)n * 4);
  char*  zbase  = base + off;
  int*   hist   = (int*)carve((size_t)n * 4);
  float* ssum   = (float*)carve(512);
  float* ssq    = (float*)carve(512);
  size_t zlen   = (size_t)((base + off) - zbase);
  float* scale  = (float*)carve(512);
  float* shift  = (float*)carve(512);
  int*   bsums  = (int*)carve(512);
  int*   coff   = (int*)carve(512);
  (void)ws_size; (void)n_in; (void)out_size;

  const int nchunk = (n + 1023) / 1024;  // 98 (<=128 required)

  hipMemsetAsync(zbase, 0, zlen, stream);
  transpose_W_kernel<<<64, 256, 0, stream>>>(W, Wt);
  linear_kernel<<<n / 32, 256, 0, stream>>>(x, Wt, bias, h, n);
  hist_kernel<<<2048, 256, 0, stream>>>(row, hist, e, n);
  scan_chunksum_kernel<<<nchunk, 256, 0, stream>>>(hist, bsums, n);
  scan_offsets_kernel<<<1, 128, 0, stream>>>(bsums, coff, rowptr, nchunk, n, e);
  scan_final_kernel<<<nchunk, 256, 0, stream>>>(hist, coff, rowptr, cursor, n);
  scatter_kernel<<<2048, 256, 0, stream>>>(row, col, cursor, scol, e, n);
  agg_kernel<<<3200, 256, 0, stream>>>(h, rowptr, scol, out, ssum, ssq, n);
  finalize_kernel<<<1, 128, 0, stream>>>(ssum, ssq, gamma, beta, scale, shift, n);
  bn_kernel<<<2048, 256, 0, stream>>>(out, scale, shift, n);
}

// Round 4
// 379.225 us; speedup vs baseline: 1.4935x; 1.3545x over previous
//
#include <hip/hip_runtime.h>

#define BN_EPS_F 1e-5f
#define MAXB 128          // max coarse buckets (node >> 10); n <= 131072
#define BIN_CHUNK 4096
#define BIN_EPT 16        // edges per thread in bin_kernel (256 thr * 16 = 4096)

static __device__ __forceinline__ float bf2f(unsigned short u) {
  union { unsigned int i; float f; } c; c.i = ((unsigned int)u) << 16; return c.f;
}
static __device__ __forceinline__ unsigned short f2bf(float f) {
  union { float f; unsigned int i; } c; c.f = f;
  unsigned int r = c.i + 0x7FFFu + ((c.i >> 16) & 1u);
  return (unsigned short)(r >> 16);
}

// ---------------- k0: W (128x128, row-major [j][k]) -> Wt[k][j] ----------------
__global__ void transpose_W_kernel(const float* __restrict__ W, float* __restrict__ Wt) {
  int idx = blockIdx.x * 256 + threadIdx.x;
  if (idx < 128 * 128) {
    int j = idx >> 7, k = idx & 127;
    Wt[(k << 7) + j] = W[idx];
  }
}

// ---------------- k1: h = x @ W.T + b -> bf16 h ----------------
__global__ __launch_bounds__(256) void linear_kernel(
    const float* __restrict__ x, const float* __restrict__ Wt,
    const float* __restrict__ bias, unsigned short* __restrict__ h, int n_nodes) {
  __shared__ float xt[32 * 128];
  const int t = threadIdx.x;
  const int tile = blockIdx.x << 5;
  {
    const float4* xg = reinterpret_cast<const float4*>(x) + ((size_t)tile << 5);
    float4* xl = reinterpret_cast<float4*>(xt);
#pragma unroll
    for (int i = 0; i < 4; ++i) xl[t + i * 256] = xg[t + i * 256];
  }
  __syncthreads();
  const int jq = (t & 31) << 2;
  const int g = t >> 5;
  const float* xr0 = &xt[(g * 4 + 0) << 7];
  const float* xr1 = &xt[(g * 4 + 1) << 7];
  const float* xr2 = &xt[(g * 4 + 2) << 7];
  const float* xr3 = &xt[(g * 4 + 3) << 7];
  float4 a0 = {0, 0, 0, 0}, a1 = {0, 0, 0, 0}, a2 = {0, 0, 0, 0}, a3 = {0, 0, 0, 0};
#pragma unroll 8
  for (int k = 0; k < 128; ++k) {
    float4 w = *reinterpret_cast<const float4*>(&Wt[(k << 7) + jq]);
    float x0 = xr0[k], x1 = xr1[k], x2 = xr2[k], x3 = xr3[k];
    a0.x = fmaf(x0, w.x, a0.x); a0.y = fmaf(x0, w.y, a0.y);
    a0.z = fmaf(x0, w.z, a0.z); a0.w = fmaf(x0, w.w, a0.w);
    a1.x = fmaf(x1, w.x, a1.x); a1.y = fmaf(x1, w.y, a1.y);
    a1.z = fmaf(x1, w.z, a1.z); a1.w = fmaf(x1, w.w, a1.w);
    a2.x = fmaf(x2, w.x, a2.x); a2.y = fmaf(x2, w.y, a2.y);
    a2.z = fmaf(x2, w.z, a2.z); a2.w = fmaf(x2, w.w, a2.w);
    a3.x = fmaf(x3, w.x, a3.x); a3.y = fmaf(x3, w.y, a3.y);
    a3.z = fmaf(x3, w.z, a3.z); a3.w = fmaf(x3, w.w, a3.w);
  }
  float4 bb = *reinterpret_cast<const float4*>(&bias[jq]);
  a0.x += bb.x; a0.y += bb.y; a0.z += bb.z; a0.w += bb.w;
  a1.x += bb.x; a1.y += bb.y; a1.z += bb.z; a1.w += bb.w;
  a2.x += bb.x; a2.y += bb.y; a2.z += bb.z; a2.w += bb.w;
  a3.x += bb.x; a3.y += bb.y; a3.z += bb.z; a3.w += bb.w;
  const int nb = tile + (g << 2);
  ushort4 p0 = {f2bf(a0.x), f2bf(a0.y), f2bf(a0.z), f2bf(a0.w)};
  ushort4 p1 = {f2bf(a1.x), f2bf(a1.y), f2bf(a1.z), f2bf(a1.w)};
  ushort4 p2 = {f2bf(a2.x), f2bf(a2.y), f2bf(a2.z), f2bf(a2.w)};
  ushort4 p3 = {f2bf(a3.x), f2bf(a3.y), f2bf(a3.z), f2bf(a3.w)};
  *reinterpret_cast<ushort4*>(&h[((size_t)(nb + 0) << 7) + jq]) = p0;
  *reinterpret_cast<ushort4*>(&h[((size_t)(nb + 1) << 7) + jq]) = p1;
  *reinterpret_cast<ushort4*>(&h[((size_t)(nb + 2) << 7) + jq]) = p2;
  *reinterpret_cast<ushort4*>(&h[((size_t)(nb + 3) << 7) + jq]) = p3;
}

// ---------------- k2: coarse bucket histogram (bucket = row >> 10) ----------------
__global__ __launch_bounds__(256) void bucket_hist_kernel(
    const int* __restrict__ row, int* __restrict__ bhist, int e_total, int nb) {
  __shared__ int bh[MAXB];
  const int t = threadIdx.x;
  if (t < MAXB) bh[t] = 0;
  __syncthreads();
  int i = blockIdx.x * 256 + t;
  const int stride = gridDim.x * 256;
  for (; i < e_total; i += stride) atomicAdd(&bh[row[i] >> 10], 1);
  __syncthreads();
  if (t < nb) {
    int c = bh[t];
    if (c) atomicAdd(&bhist[t], c);
  }
}

// ---------------- k3: exclusive scan of bucket hist -> bbase, bcursor ----------------
__global__ void bucket_scan_kernel(const int* __restrict__ bhist, int* __restrict__ bbase,
                                   int* __restrict__ bcursor, int nb, int e_total) {
  __shared__ int sd[MAXB];
  const int t = threadIdx.x;  // 128
  int v = (t < nb) ? bhist[t] : 0;
  sd[t] = v;
  __syncthreads();
  for (int off = 1; off < MAXB; off <<= 1) {
    int u = (t >= off) ? sd[t - off] : 0;
    __syncthreads();
    sd[t] += u;
    __syncthreads();
  }
  int excl = sd[t] - v;
  if (t < nb) { bbase[t] = excl; bcursor[t] = excl; }
  if (t == 0) bbase[nb] = e_total;
}

// ---------------- k4: bin edges into coarse buckets, packed (lr<<17)|col ----------------
__global__ __launch_bounds__(256) void bin_kernel(
    const int* __restrict__ row, const int* __restrict__ col,
    int* __restrict__ bcursor, unsigned int* __restrict__ pairs, int e_total, int nb) {
  __shared__ int scount[MAXB];
  __shared__ int gbase[MAXB];
  const int t = threadIdx.x;
  if (t < MAXB) scount[t] = 0;
  __syncthreads();
  const int base = blockIdx.x * BIN_CHUNK;
  int bkt[BIN_EPT], slot[BIN_EPT];
  unsigned int pk[BIN_EPT];
#pragma unroll
  for (int k = 0; k < BIN_EPT; ++k) {
    int i = base + t + (k << 8);
    bkt[k] = -1;
    if (i < e_total) {
      int r = row[i], c = col[i];
      bkt[k] = r >> 10;
      pk[k] = ((unsigned int)(r & 1023) << 17) | (unsigned int)c;
      slot[k] = atomicAdd(&scount[bkt[k]], 1);
    }
  }
  __syncthreads();
  if (t < nb) {
    int c = scount[t];
    gbase[t] = c ? atomicAdd(&bcursor[t], c) : 0;
  }
  __syncthreads();
#pragma unroll
  for (int k = 0; k < BIN_EPT; ++k) {
    if (bkt[k] >= 0) pairs[gbase[bkt[k]] + slot[k]] = pk[k];
  }
}

// ---------------- k5: per-bucket CSR build (rowptr + scol), all L2-local ----------------
__global__ __launch_bounds__(256) void csr_kernel(
    const unsigned int* __restrict__ pairs, const int* __restrict__ bbase,
    int* __restrict__ rowptr, int* __restrict__ scol, int n, int e_total) {
  __shared__ int lh[1024];
  __shared__ int sscan[256];
  const int b = blockIdx.x;
  const int t = threadIdx.x;
  const int node_base = b << 10;
  const int nn = min(1024, n - node_base);
  const int p0 = bbase[b], p1 = bbase[b + 1];
  for (int j = t; j < 1024; j += 256) lh[j] = 0;
  __syncthreads();
  for (int i = p0 + t; i < p1; i += 256) {
    atomicAdd(&lh[pairs[i] >> 17], 1);
  }
  __syncthreads();
  const int v0 = lh[4 * t + 0], v1 = lh[4 * t + 1], v2 = lh[4 * t + 2], v3 = lh[4 * t + 3];
  const int s = v0 + v1 + v2 + v3;
  sscan[t] = s;
  __syncthreads();
  for (int off = 1; off < 256; off <<= 1) {
    int u = (t >= off) ? sscan[t - off] : 0;
    __syncthreads();
    sscan[t] += u;
    __syncthreads();
  }
  const int excl = sscan[t] - s;
  const int c0 = excl, c1 = excl + v0, c2 = c1 + v1, c3 = c2 + v2;
  if (4 * t + 0 < nn) rowptr[node_base + 4 * t + 0] = p0 + c0;
  if (4 * t + 1 < nn) rowptr[node_base + 4 * t + 1] = p0 + c1;
  if (4 * t + 2 < nn) rowptr[node_base + 4 * t + 2] = p0 + c2;
  if (4 * t + 3 < nn) rowptr[node_base + 4 * t + 3] = p0 + c3;
  __syncthreads();  // all lh reads done; safe to overwrite as cursor
  lh[4 * t + 0] = c0; lh[4 * t + 1] = c1; lh[4 * t + 2] = c2; lh[4 * t + 3] = c3;
  __syncthreads();
  for (int i = p0 + t; i < p1; i += 256) {
    unsigned int p = pairs[i];
    int pl = atomicAdd(&lh[p >> 17], 1);
    scol[p0 + pl] = (int)(p & 0x1FFFFu);
  }
  if (b == 0 && t == 0) rowptr[n] = e_total;
}

// ---------------- k6: out_pre = h + mean-agg (bf16 gather); accumulate sum/sumsq ----------------
__global__ __launch_bounds__(256) void agg_kernel(
    const unsigned short* __restrict__ h, const int* __restrict__ rowptr,
    const int* __restrict__ scol, float* __restrict__ out,
    float* __restrict__ stat_sum, float* __restrict__ stat_sumsq, int n_nodes) {
  const int t = threadIdx.x;
  const int wave = t >> 6, lane = t & 63;
  const int f0 = lane << 1;
  float lsx = 0.f, lsy = 0.f, lqx = 0.f, lqy = 0.f;
  const int wstride = gridDim.x << 2;
  for (int node = (blockIdx.x << 2) + wave; node < n_nodes; node += wstride) {
    const int r0 = rowptr[node], r1 = rowptr[node + 1];
    ushort2 hv = *reinterpret_cast<const ushort2*>(&h[((size_t)node << 7) + f0]);
    float s0x = 0.f, s0y = 0.f, s1x = 0.f, s1y = 0.f;
    int e = r0;
    for (; e + 3 < r1; e += 4) {
      int c0 = scol[e], c1 = scol[e + 1], c2 = scol[e + 2], c3 = scol[e + 3];
      ushort2 v0 = *reinterpret_cast<const ushort2*>(&h[((size_t)c0 << 7) + f0]);
      ushort2 v1 = *reinterpret_cast<const ushort2*>(&h[((size_t)c1 << 7) + f0]);
      ushort2 v2 = *reinterpret_cast<const ushort2*>(&h[((size_t)c2 << 7) + f0]);
      ushort2 v3 = *reinterpret_cast<const ushort2*>(&h[((size_t)c3 << 7) + f0]);
      s0x += bf2f(v0.x); s0y += bf2f(v0.y);
      s1x += bf2f(v1.x); s1y += bf2f(v1.y);
      s0x += bf2f(v2.x); s0y += bf2f(v2.y);
      s1x += bf2f(v3.x); s1y += bf2f(v3.y);
    }
    for (; e < r1; ++e) {
      int c0 = scol[e];
      ushort2 v0 = *reinterpret_cast<const ushort2*>(&h[((size_t)c0 << 7) + f0]);
      s0x += bf2f(v0.x); s0y += bf2f(v0.y);
    }
    const float inv = 1.0f / ((float)(r1 - r0) + 1e-8f);
    const float vx = fmaf(s0x + s1x, inv, bf2f(hv.x));
    const float vy = fmaf(s0y + s1y, inv, bf2f(hv.y));
    float2 o; o.x = vx; o.y = vy;
    *reinterpret_cast<float2*>(&out[((size_t)node << 7) + f0]) = o;
    lsx += vx; lsy += vy;
    lqx = fmaf(vx, vx, lqx); lqy = fmaf(vy, vy, lqy);
  }
  __shared__ float reds[4][128];
  __shared__ float redq[4][128];
  reds[wave][f0] = lsx; reds[wave][f0 + 1] = lsy;
  redq[wave][f0] = lqx; redq[wave][f0 + 1] = lqy;
  __syncthreads();
  if (t < 128) {
    float s = reds[0][t] + reds[1][t] + reds[2][t] + reds[3][t];
    float q = redq[0][t] + redq[1][t] + redq[2][t] + redq[3][t];
    atomicAdd(&stat_sum[t], s);
    atomicAdd(&stat_sumsq[t], q);
  }
}

// ---------------- k7: BN stats -> per-feature scale/shift ----------------
__global__ void finalize_kernel(const float* __restrict__ ssum, const float* __restrict__ ssq,
                                const float* __restrict__ gamma, const float* __restrict__ beta,
                                float* __restrict__ scale, float* __restrict__ shift, int n) {
  const int t = threadIdx.x;  // 128
  const float invn = 1.0f / (float)n;
  float mean = ssum[t] * invn;
  float var = ssq[t] * invn - mean * mean;
  float sc = gamma[t] * rsqrtf(var + BN_EPS_F);
  scale[t] = sc;
  shift[t] = beta[t] - mean * sc;
}

// ---------------- k8: BN apply in-place on d_out ----------------
__global__ __launch_bounds__(256) void bn_kernel(float* __restrict__ out,
                                                 const float* __restrict__ scale,
                                                 const float* __restrict__ shift, int n_nodes) {
  __shared__ float sc[128], sh[128];
  if (threadIdx.x < 128) {
    sc[threadIdx.x] = scale[threadIdx.x];
    sh[threadIdx.x] = shift[threadIdx.x];
  }
  __syncthreads();
  const int total4 = n_nodes * 32;
  int i = blockIdx.x * 256 + threadIdx.x;
  const int stride = gridDim.x * 256;
  float4* o4 = reinterpret_cast<float4*>(out);
  for (; i < total4; i += stride) {
    float4 v = o4[i];
    const int fq = (i & 31) << 2;
    v.x = fmaf(v.x, sc[fq + 0], sh[fq + 0]);
    v.y = fmaf(v.y, sc[fq + 1], sh[fq + 1]);
    v.z = fmaf(v.z, sc[fq + 2], sh[fq + 2]);
    v.w = fmaf(v.w, sc[fq + 3], sh[fq + 3]);
    o4[i] = v;
  }
}

extern "C" void kernel_launch(void* const* d_in, const int* in_sizes, int n_in,
                              void* d_out, int out_size, void* d_ws, size_t ws_size,
                              hipStream_t stream) {
  const float* x     = (const float*)d_in[0];
  const int*   ei    = (const int*)d_in[1];
  const float* W     = (const float*)d_in[2];
  const float* bias  = (const float*)d_in[3];
  const float* gamma = (const float*)d_in[4];
  const float* beta  = (const float*)d_in[5];
  const int n = in_sizes[0] / 128;   // 100000
  const int e = in_sizes[1] / 2;     // 1600000
  const int* row = ei;
  const int* col = ei + e;
  float* out = (float*)d_out;

  char* base = (char*)d_ws;
  size_t off = 0;
  auto carve = [&](size_t bytes) -> char* {
    char* p = base + off;
    off += (bytes + 255) & ~(size_t)255;
    return p;
  };
  unsigned short* h = (unsigned short*)carve((size_t)n * 128 * 2);  // 25.6 MB
  float* Wt       = (float*)carve(128 * 128 * 4);                   // 64 KB
  unsigned int* pairs = (unsigned int*)carve((size_t)e * 4);        // 6.4 MB
  int*   scol     = (int*)carve((size_t)e * 4);                     // 6.4 MB
  int*   rowptr   = (int*)carve((size_t)(n + 1) * 4);
  int*   bcursor  = (int*)carve(MAXB * 4);
  int*   bbase    = (int*)carve((MAXB + 1) * 4);
  float* scale    = (float*)carve(512);
  float* shift    = (float*)carve(512);
  char*  zbase    = base + off;
  int*   bhist    = (int*)carve(MAXB * 4);
  float* ssum     = (float*)carve(512);
  float* ssq      = (float*)carve(512);
  size_t zlen     = (size_t)((base + off) - zbase);
  (void)ws_size; (void)n_in; (void)out_size;

  const int nb = (n + 1023) >> 10;  // 98 (<= MAXB required)
  const int bin_grid = (e + BIN_CHUNK - 1) / BIN_CHUNK;  // 391

  hipMemsetAsync(zbase, 0, zlen, stream);
  transpose_W_kernel<<<64, 256, 0, stream>>>(W, Wt);
  linear_kernel<<<n / 32, 256, 0, stream>>>(x, Wt, bias, h, n);
  bucket_hist_kernel<<<256, 256, 0, stream>>>(row, bhist, e, nb);
  bucket_scan_kernel<<<1, MAXB, 0, stream>>>(bhist, bbase, bcursor, nb, e);
  bin_kernel<<<bin_grid, 256, 0, stream>>>(row, col, bcursor, pairs, e, nb);
  csr_kernel<<<nb, 256, 0, stream>>>(pairs, bbase, rowptr, scol, n, e);
  agg_kernel<<<3200, 256, 0, stream>>>(h, rowptr, scol, out, ssum, ssq, n);
  finalize_kernel<<<1, 128, 0, stream>>>(ssum, ssq, gamma, beta, scale, shift, n);
  bn_kernel<<<2048, 256, 0, stream>>>(out, scale, shift, n);
}

// Round 5
// 348.958 us; speedup vs baseline: 1.6231x; 1.0867x over previous
//
#include <hip/hip_runtime.h>

#define BN_EPS_F 1e-5f
#define MAXB 128          // max coarse buckets (node >> 10); n <= 131072
#define BIN_CHUNK 4096
#define BIN_EPT 16        // edges per thread in bin_kernel (256 thr * 16 = 4096)

typedef __attribute__((ext_vector_type(8))) short bf16x8;
typedef __attribute__((ext_vector_type(4))) float f32x4;

static __device__ __forceinline__ float bf2f(unsigned short u) {
  union { unsigned int i; float f; } c; c.i = ((unsigned int)u) << 16; return c.f;
}
static __device__ __forceinline__ unsigned short f2bf(float f) {
  union { float f; unsigned int i; } c; c.f = f;
  unsigned int r = c.i + 0x7FFFu + ((c.i >> 16) & 1u);
  return (unsigned short)(r >> 16);
}

// ---------------- k0: W (128x128 row-major [j][k]) -> B-fragment layout bf16 ----------------
// wfrag[((jt*4+kk)*64 + l)*8 + e] = bf16(W[jt*16 + (l&15)][kk*32 + (l>>4)*8 + e])
__global__ void wfrag_kernel(const float* __restrict__ W, unsigned short* __restrict__ wfrag) {
  int idx = blockIdx.x * 256 + threadIdx.x;  // 0..16383
  int e = idx & 7, l = (idx >> 3) & 63, kk = (idx >> 9) & 3, jt = idx >> 11;
  int j = jt * 16 + (l & 15);
  int k = kk * 32 + ((l >> 4) << 3) + e;
  wfrag[idx] = f2bf(W[j * 128 + k]);
}

// ---------------- k1: h = x @ W.T + b -> bf16 h, via MFMA 16x16x32 bf16 ----------------
// Block 256 thr = 4 waves; wave w computes rows [blk*64 + w*16, +16) x all 128 cols.
// A-frag: lane holds x[row=base+(l&15)][kk*32 + (l>>4)*8 + 0..7] (global direct, no LDS).
// 8 col-tiles x 4 K-steps = 32 MFMA per wave. Epilogue via per-wave LDS repack.
__global__ __launch_bounds__(256) void linear_kernel(
    const float* __restrict__ x, const unsigned short* __restrict__ wfrag,
    const float* __restrict__ bias, ushort4* __restrict__ h4, int n) {
  __shared__ unsigned short els[4][16 * 128];
  const int t = threadIdx.x;
  const int w = t >> 6, lane = t & 63;
  const int base = blockIdx.x * 64 + w * 16;
  const int row = base + (lane & 15);
  const int rowc = row < n ? row : (n - 1);
  const float4* xr = reinterpret_cast<const float4*>(x) + (size_t)rowc * 32;
  const bf16x8* bf = reinterpret_cast<const bf16x8*>(wfrag);

  f32x4 acc[8];
#pragma unroll
  for (int jt = 0; jt < 8; ++jt) acc[jt] = (f32x4){0.f, 0.f, 0.f, 0.f};

#pragma unroll
  for (int kk = 0; kk < 4; ++kk) {
    float4 lo = xr[kk * 8 + ((lane >> 4) << 1)];
    float4 hi = xr[kk * 8 + ((lane >> 4) << 1) + 1];
    bf16x8 a;
    a[0] = (short)f2bf(lo.x); a[1] = (short)f2bf(lo.y);
    a[2] = (short)f2bf(lo.z); a[3] = (short)f2bf(lo.w);
    a[4] = (short)f2bf(hi.x); a[5] = (short)f2bf(hi.y);
    a[6] = (short)f2bf(hi.z); a[7] = (short)f2bf(hi.w);
#pragma unroll
    for (int jt = 0; jt < 8; ++jt) {
      bf16x8 b = bf[(jt * 4 + kk) * 64 + lane];
      acc[jt] = __builtin_amdgcn_mfma_f32_16x16x32_bf16(a, b, acc[jt], 0, 0, 0);
    }
  }

  // Epilogue: add bias, pack bf16 into wave-private LDS, coalesced store.
  unsigned short* ep = els[w];
#pragma unroll
  for (int jt = 0; jt < 8; ++jt) {
    float bv = bias[jt * 16 + (lane & 15)];
#pragma unroll
    for (int r = 0; r < 4; ++r) {
      int orow = ((lane >> 4) << 2) + r;
      ep[orow * 128 + jt * 16 + (lane & 15)] = f2bf(acc[jt][r] + bv);
    }
  }
  const ushort4* ep4 = reinterpret_cast<const ushort4*>(ep);
#pragma unroll
  for (int i = 0; i < 8; ++i) {
    int idx = i * 64 + lane;
    int r2 = idx >> 5, c4 = idx & 31;
    int grow = base + r2;
    if (grow < n) h4[(size_t)grow * 32 + c4] = ep4[idx];
  }
}

// ---------------- k2: coarse bucket histogram (bucket = row >> 10) ----------------
__global__ __launch_bounds__(256) void bucket_hist_kernel(
    const int* __restrict__ row, int* __restrict__ bhist, int e_total, int nb) {
  __shared__ int bh[MAXB];
  const int t = threadIdx.x;
  if (t < MAXB) bh[t] = 0;
  __syncthreads();
  int i = blockIdx.x * 256 + t;
  const int stride = gridDim.x * 256;
  for (; i < e_total; i += stride) atomicAdd(&bh[row[i] >> 10], 1);
  __syncthreads();
  if (t < nb) {
    int c = bh[t];
    if (c) atomicAdd(&bhist[t], c);
  }
}

// ---------------- k3: exclusive scan of bucket hist -> bbase, bcursor ----------------
__global__ void bucket_scan_kernel(const int* __restrict__ bhist, int* __restrict__ bbase,
                                   int* __restrict__ bcursor, int nb, int e_total) {
  __shared__ int sd[MAXB];
  const int t = threadIdx.x;  // MAXB
  int v = (t < nb) ? bhist[t] : 0;
  sd[t] = v;
  __syncthreads();
  for (int off = 1; off < MAXB; off <<= 1) {
    int u = (t >= off) ? sd[t - off] : 0;
    __syncthreads();
    sd[t] += u;
    __syncthreads();
  }
  int excl = sd[t] - v;
  if (t < nb) { bbase[t] = excl; bcursor[t] = excl; }
  if (t == 0) bbase[nb] = e_total;
}

// ---------------- k4: bin edges into coarse buckets, packed (lr<<17)|col ----------------
__global__ __launch_bounds__(256) void bin_kernel(
    const int* __restrict__ row, const int* __restrict__ col,
    int* __restrict__ bcursor, unsigned int* __restrict__ pairs, int e_total, int nb) {
  __shared__ int scount[MAXB];
  __shared__ int gbase[MAXB];
  const int t = threadIdx.x;
  if (t < MAXB) scount[t] = 0;
  __syncthreads();
  const int base = blockIdx.x * BIN_CHUNK;
  int bkt[BIN_EPT], slot[BIN_EPT];
  unsigned int pk[BIN_EPT];
#pragma unroll
  for (int k = 0; k < BIN_EPT; ++k) {
    int i = base + t + (k << 8);
    bkt[k] = -1;
    if (i < e_total) {
      int r = row[i], c = col[i];
      bkt[k] = r >> 10;
      pk[k] = ((unsigned int)(r & 1023) << 17) | (unsigned int)c;
      slot[k] = atomicAdd(&scount[bkt[k]], 1);
    }
  }
  __syncthreads();
  if (t < nb) {
    int c = scount[t];
    gbase[t] = c ? atomicAdd(&bcursor[t], c) : 0;
  }
  __syncthreads();
#pragma unroll
  for (int k = 0; k < BIN_EPT; ++k) {
    if (bkt[k] >= 0) pairs[gbase[bkt[k]] + slot[k]] = pk[k];
  }
}

// ---------------- k5: per-bucket CSR build (rowptr + scol), all L2-local ----------------
__global__ __launch_bounds__(256) void csr_kernel(
    const unsigned int* __restrict__ pairs, const int* __restrict__ bbase,
    int* __restrict__ rowptr, int* __restrict__ scol, int n, int e_total) {
  __shared__ int lh[1024];
  __shared__ int sscan[256];
  const int b = blockIdx.x;
  const int t = threadIdx.x;
  const int node_base = b << 10;
  const int nn = min(1024, n - node_base);
  const int p0 = bbase[b], p1 = bbase[b + 1];
  for (int j = t; j < 1024; j += 256) lh[j] = 0;
  __syncthreads();
  for (int i = p0 + t; i < p1; i += 256) {
    atomicAdd(&lh[pairs[i] >> 17], 1);
  }
  __syncthreads();
  const int v0 = lh[4 * t + 0], v1 = lh[4 * t + 1], v2 = lh[4 * t + 2], v3 = lh[4 * t + 3];
  const int s = v0 + v1 + v2 + v3;
  sscan[t] = s;
  __syncthreads();
  for (int off = 1; off < 256; off <<= 1) {
    int u = (t >= off) ? sscan[t - off] : 0;
    __syncthreads();
    sscan[t] += u;
    __syncthreads();
  }
  const int excl = sscan[t] - s;
  const int c0 = excl, c1 = excl + v0, c2 = c1 + v1, c3 = c2 + v2;
  if (4 * t + 0 < nn) rowptr[node_base + 4 * t + 0] = p0 + c0;
  if (4 * t + 1 < nn) rowptr[node_base + 4 * t + 1] = p0 + c1;
  if (4 * t + 2 < nn) rowptr[node_base + 4 * t + 2] = p0 + c2;
  if (4 * t + 3 < nn) rowptr[node_base + 4 * t + 3] = p0 + c3;
  __syncthreads();  // all lh reads done; safe to overwrite as cursor
  lh[4 * t + 0] = c0; lh[4 * t + 1] = c1; lh[4 * t + 2] = c2; lh[4 * t + 3] = c3;
  __syncthreads();
  for (int i = p0 + t; i < p1; i += 256) {
    unsigned int p = pairs[i];
    int pl = atomicAdd(&lh[p >> 17], 1);
    scol[p0 + pl] = (int)(p & 0x1FFFFu);
  }
  if (b == 0 && t == 0) rowptr[n] = e_total;
}

// ---------------- k6: out = h + mean-agg (bf16 gather, 32 lanes/edge); stats ----------------
// Wave per node; half = lane>>5 handles alternating edges; lane covers feature quad q=lane&31.
__global__ __launch_bounds__(256) void agg_kernel(
    const ushort4* __restrict__ h4, const int* __restrict__ rowptr,
    const int* __restrict__ scol, float* __restrict__ out,
    float* __restrict__ stat_sum, float* __restrict__ stat_sumsq, int n_nodes) {
  const int t = threadIdx.x;
  const int wave = t >> 6, lane = t & 63;
  const int half = lane >> 5, q = lane & 31;
  float ls0 = 0.f, ls1 = 0.f, ls2 = 0.f, ls3 = 0.f;
  float lq0 = 0.f, lq1 = 0.f, lq2 = 0.f, lq3 = 0.f;
  const int wstride = gridDim.x << 2;
  for (int node = (blockIdx.x << 2) + wave; node < n_nodes; node += wstride) {
    const int r0 = rowptr[node], r1 = rowptr[node + 1];
    float a0 = 0.f, a1 = 0.f, a2 = 0.f, a3 = 0.f;
    int e = r0 + half;
    for (; e + 2 < r1; e += 4) {
      int c0 = scol[e], c1 = scol[e + 2];
      ushort4 v0 = h4[(size_t)c0 * 32 + q];
      ushort4 v1 = h4[(size_t)c1 * 32 + q];
      a0 += bf2f(v0.x) + bf2f(v1.x);
      a1 += bf2f(v0.y) + bf2f(v1.y);
      a2 += bf2f(v0.z) + bf2f(v1.z);
      a3 += bf2f(v0.w) + bf2f(v1.w);
    }
    if (e < r1) {
      int c0 = scol[e];
      ushort4 v0 = h4[(size_t)c0 * 32 + q];
      a0 += bf2f(v0.x); a1 += bf2f(v0.y); a2 += bf2f(v0.z); a3 += bf2f(v0.w);
    }
    a0 += __shfl_xor(a0, 32, 64);
    a1 += __shfl_xor(a1, 32, 64);
    a2 += __shfl_xor(a2, 32, 64);
    a3 += __shfl_xor(a3, 32, 64);
    if (half == 0) {
      ushort4 hv = h4[(size_t)node * 32 + q];
      const float inv = 1.0f / ((float)(r1 - r0) + 1e-8f);
      float v0 = fmaf(a0, inv, bf2f(hv.x));
      float v1 = fmaf(a1, inv, bf2f(hv.y));
      float v2 = fmaf(a2, inv, bf2f(hv.z));
      float v3 = fmaf(a3, inv, bf2f(hv.w));
      float4 o; o.x = v0; o.y = v1; o.z = v2; o.w = v3;
      *reinterpret_cast<float4*>(&out[(size_t)node * 128 + q * 4]) = o;
      ls0 += v0; ls1 += v1; ls2 += v2; ls3 += v3;
      lq0 = fmaf(v0, v0, lq0); lq1 = fmaf(v1, v1, lq1);
      lq2 = fmaf(v2, v2, lq2); lq3 = fmaf(v3, v3, lq3);
    }
  }
  __shared__ float reds[4][128];
  __shared__ float redq[4][128];
  if (half == 0) {
    float4 s; s.x = ls0; s.y = ls1; s.z = ls2; s.w = ls3;
    float4 qq; qq.x = lq0; qq.y = lq1; qq.z = lq2; qq.w = lq3;
    *reinterpret_cast<float4*>(&reds[wave][q * 4]) = s;
    *reinterpret_cast<float4*>(&redq[wave][q * 4]) = qq;
  }
  __syncthreads();
  if (t < 128) {
    float s = reds[0][t] + reds[1][t] + reds[2][t] + reds[3][t];
    float qv = redq[0][t] + redq[1][t] + redq[2][t] + redq[3][t];
    atomicAdd(&stat_sum[t], s);
    atomicAdd(&stat_sumsq[t], qv);
  }
}

// ---------------- k7: BN stats -> per-feature scale/shift ----------------
__global__ void finalize_kernel(const float* __restrict__ ssum, const float* __restrict__ ssq,
                                const float* __restrict__ gamma, const float* __restrict__ beta,
                                float* __restrict__ scale, float* __restrict__ shift, int n) {
  const int t = threadIdx.x;  // 128
  const float invn = 1.0f / (float)n;
  float mean = ssum[t] * invn;
  float var = ssq[t] * invn - mean * mean;
  float sc = gamma[t] * rsqrtf(var + BN_EPS_F);
  scale[t] = sc;
  shift[t] = beta[t] - mean * sc;
}

// ---------------- k8: BN apply in-place on d_out ----------------
__global__ __launch_bounds__(256) void bn_kernel(float* __restrict__ out,
                                                 const float* __restrict__ scale,
                                                 const float* __restrict__ shift, int n_nodes) {
  __shared__ float sc[128], sh[128];
  if (threadIdx.x < 128) {
    sc[threadIdx.x] = scale[threadIdx.x];
    sh[threadIdx.x] = shift[threadIdx.x];
  }
  __syncthreads();
  const int total4 = n_nodes * 32;
  int i = blockIdx.x * 256 + threadIdx.x;
  const int stride = gridDim.x * 256;
  float4* o4 = reinterpret_cast<float4*>(out);
  for (; i < total4; i += stride) {
    float4 v = o4[i];
    const int fq = (i & 31) << 2;
    v.x = fmaf(v.x, sc[fq + 0], sh[fq + 0]);
    v.y = fmaf(v.y, sc[fq + 1], sh[fq + 1]);
    v.z = fmaf(v.z, sc[fq + 2], sh[fq + 2]);
    v.w = fmaf(v.w, sc[fq + 3], sh[fq + 3]);
    o4[i] = v;
  }
}

extern "C" void kernel_launch(void* const* d_in, const int* in_sizes, int n_in,
                              void* d_out, int out_size, void* d_ws, size_t ws_size,
                              hipStream_t stream) {
  const float* x     = (const float*)d_in[0];
  const int*   ei    = (const int*)d_in[1];
  const float* W     = (const float*)d_in[2];
  const float* bias  = (const float*)d_in[3];
  const float* gamma = (const float*)d_in[4];
  const float* beta  = (const float*)d_in[5];
  const int n = in_sizes[0] / 128;   // 100000
  const int e = in_sizes[1] / 2;     // 1600000
  const int* row = ei;
  const int* col = ei + e;
  float* out = (float*)d_out;

  char* base = (char*)d_ws;
  size_t off = 0;
  auto carve = [&](size_t bytes) -> char* {
    char* p = base + off;
    off += (bytes + 255) & ~(size_t)255;
    return p;
  };
  unsigned short* h = (unsigned short*)carve((size_t)n * 128 * 2);  // 25.6 MB
  unsigned short* wfrag = (unsigned short*)carve(128 * 128 * 2);    // 32 KB
  unsigned int* pairs = (unsigned int*)carve((size_t)e * 4);        // 6.4 MB
  int*   scol     = (int*)carve((size_t)e * 4);                     // 6.4 MB
  int*   rowptr   = (int*)carve((size_t)(n + 1) * 4);
  int*   bcursor  = (int*)carve(MAXB * 4);
  int*   bbase    = (int*)carve((MAXB + 1) * 4);
  float* scale    = (float*)carve(512);
  float* shift    = (float*)carve(512);
  char*  zbase    = base + off;
  int*   bhist    = (int*)carve(MAXB * 4);
  float* ssum     = (float*)carve(512);
  float* ssq      = (float*)carve(512);
  size_t zlen     = (size_t)((base + off) - zbase);
  (void)ws_size; (void)n_in; (void)out_size;

  const int nb = (n + 1023) >> 10;  // 98 (<= MAXB required)
  const int bin_grid = (e + BIN_CHUNK - 1) / BIN_CHUNK;  // 391
  const int lin_grid = (n + 63) / 64;                    // 1563

  hipMemsetAsync(zbase, 0, zlen, stream);
  wfrag_kernel<<<64, 256, 0, stream>>>(W, wfrag);
  linear_kernel<<<lin_grid, 256, 0, stream>>>(x, wfrag, bias, (ushort4*)h, n);
  bucket_hist_kernel<<<256, 256, 0, stream>>>(row, bhist, e, nb);
  bucket_scan_kernel<<<1, MAXB, 0, stream>>>(bhist, bbase, bcursor, nb, e);
  bin_kernel<<<bin_grid, 256, 0, stream>>>(row, col, bcursor, pairs, e, nb);
  csr_kernel<<<nb, 256, 0, stream>>>(pairs, bbase, rowptr, scol, n, e);
  agg_kernel<<<3200, 256, 0, stream>>>((const ushort4*)h, rowptr, scol, out, ssum, ssq, n);
  finalize_kernel<<<1, 128, 0, stream>>>(ssum, ssq, gamma, beta, scale, shift, n);
  bn_kernel<<<2048, 256, 0, stream>>>(out, scale, shift, n);
}